// Round 5
// baseline (968.749 us; speedup 1.0000x reference)
//
#include <hip/hip_runtime.h>

#define KN  50
#define NM  10          // MBON == DAN == 10
#define LPB 16          // lanes per batch element

typedef float v2f __attribute__((ext_vector_type(2)));

// mov_dpp(old=0,bound_ctrl=1) + fadd; GCNDPPCombine fuses into v_add_f32_dpp (1 inst)
template <int CTRL>
__device__ __forceinline__ float dpp_add(float x) {
  return x + __int_as_float(
      __builtin_amdgcn_update_dpp(0, __float_as_int(x), CTRL, 0xF, 0xF, true));
}

__device__ __forceinline__ float rowsum16(float x) {
  x = dpp_add<0x121>(x);   // row_ror:1
  x = dpp_add<0x122>(x);   // row_ror:2
  x = dpp_add<0x124>(x);   // row_ror:4
  x = dpp_add<0x128>(x);   // row_ror:8
  return x;                // full 16-lane sum REPLICATED into every lane
}

extern "C" __global__ void __launch_bounds__(256)
// (2,2) is the proven floor: rounds 1/3/4 showed any budget <256 regs triggers a
// spill cascade on the persistent plastic state (VGPR->64, FETCH 10-20 GB, 5-7x slow).
__attribute__((amdgpu_waves_per_eu(2, 2)))
fly_kernel(const float* __restrict__ odor,    // [T,B,3]
           const float* __restrict__ ctxp,    // [T,B,1]
           const float* __restrict__ pn_w,    // [B,3,KN]
           const float* __restrict__ kn_b,    // [KN]
           const float* __restrict__ apl_w,   // [KN,1]
           const float* __restrict__ apl_b,   // [1]
           const float* __restrict__ mdw_g,   // mbon_dan_weight [DAN,MBON]
           const float* __restrict__ mbon_b,  // [MBON]
           const float* __restrict__ dmw_g,   // dan_mbon_weight [MBON,DAN]
           const float* __restrict__ ddw_g,   // dan_dan_weight [DAN,DAN]
           const float* __restrict__ dcw_g,   // dan_context_weight [1,DAN]
           const float* __restrict__ dan_b,   // [DAN]
           const float* __restrict__ decW,    // [2,MBON]
           const float* __restrict__ decb,    // [2]
           const float* __restrict__ kcw0,    // [B,KN,MBON]
           const float* __restrict__ wact0,   // [B,KN,MBON]
           float* __restrict__ out,           // [T,B,2]
           int B, int T)
{
  const int tid   = threadIdx.x;
  const int j     = tid & (LPB - 1);
  const int jhalf = j >> 1;
  const int jodd  = j & 1;
  const int b     = blockIdx.x * (256 / LPB) + (tid >> 4);
  if (b >= B) return;

  const bool has4  = (j + 48) < KN;           // lanes 0,1 own a 4th k-row
  const bool isl10 = (j == 10);               // bias/context pseudo-row lane

  // ---- persistent plastic state + per-batch weights (VGPRs) ----
  // wct holds Bq = 0.25*wact (exact pow2 scale) -> kc_w decay is one pk_fma.
  v2f   kcw[4][5], wct[4][5];                 // rows j,16+j,32+j,48+j  x  10 cols (packed)
  float pw0[4], pw1[4], pw2[4], knb[4], aw[4];
  float kcn[4] = {0.f,0.f,0.f,0.f}, lkc[4] = {0.f,0.f,0.f,0.f};

  #pragma unroll
  for (int i = 0; i < 4; ++i) {
    const int k = j + 16 * i;
    if (i < 3 || has4) {
      const v2f* a = reinterpret_cast<const v2f*>(kcw0  + ((size_t)b * KN + k) * NM);
      const v2f* w = reinterpret_cast<const v2f*>(wact0 + ((size_t)b * KN + k) * NM);
      #pragma unroll
      for (int h = 0; h < 5; ++h) { kcw[i][h] = a[h]; wct[i][h] = 0.25f * w[h]; }
      pw0[i] = pn_w[((size_t)b * 3 + 0) * KN + k];
      pw1[i] = pn_w[((size_t)b * 3 + 1) * KN + k];
      pw2[i] = pn_w[((size_t)b * 3 + 2) * KN + k];
      knb[i] = kn_b[k];
      aw[i]  = apl_w[k];
    } else {
      #pragma unroll
      for (int h = 0; h < 5; ++h) { kcw[i][h] = (v2f)(0.f); wct[i][h] = (v2f)(0.f); }
      pw0[i] = pw1[i] = pw2[i] = 0.f; knb[i] = 0.f; aw[i] = 0.f;
    }
  }

  // ---- small-network weights ----
  // mdw: COLUMN j (for the per-column MBON gate).
  // ddw/dmw: ROW j (for the rowsum-distributed DAN matvec).
  // lane 10 pseudo-row: ddwr := dan_context_weight (factor cx), dmwr := dan_bias (factor 1).
  v2f   mdw2[5], ddwr[5], dmwr[5];
  float mb_ = 0.f, dw0 = 0.f, dw1 = 0.f;
  #pragma unroll
  for (int h = 0; h < 5; ++h) { mdw2[h] = (v2f)(0.f); ddwr[h] = (v2f)(0.f); dmwr[h] = (v2f)(0.f); }
  if (j < NM) {
    #pragma unroll
    for (int h = 0; h < 5; ++h) {
      mdw2[h].x = mdw_g[(2*h)   * NM + j];  mdw2[h].y = mdw_g[(2*h+1) * NM + j];
      ddwr[h].x = ddw_g[j * NM + 2*h];      ddwr[h].y = ddw_g[j * NM + 2*h + 1];
      dmwr[h].x = dmw_g[j * NM + 2*h];      dmwr[h].y = dmw_g[j * NM + 2*h + 1];
    }
    mb_ = mbon_b[j];
    dw0 = decW[j];
    dw1 = decW[NM + j];
  } else if (isl10) {
    #pragma unroll
    for (int h = 0; h < 5; ++h) {
      ddwr[h].x = dcw_g[2*h];   ddwr[h].y = dcw_g[2*h + 1];   // cx * dcw
      dmwr[h].x = dan_b[2*h];   dmwr[h].y = dan_b[2*h + 1];   // 1  * dan_b
    }
  }
  const float aplb = apl_b[0];
  const float db0 = decb[0], db1 = decb[1];

  const float ALPHA = (float)(0.5 / 5.5);     // DT/(DT+RC)

  // ---- recurrent small state ----
  // dvec2/ldv2: FULL dan / low_dan vectors, replicated in every lane (no broadcasts).
  // dan_m: this lane's own component (kept consistent with dvec2[j]).
  float apl = 0.f, mbon_m = 0.f, dan_m = 0.f;
  v2f dvec2[5], ldv2[5];
  #pragma unroll
  for (int h = 0; h < 5; ++h) { dvec2[h] = (v2f)(0.f); ldv2[h] = (v2f)(0.f); }

  // input pointers (strength-reduced); prefetch t=0
  const float* op = odor + (size_t)b * 3;
  const float* cp = ctxp + b;
  const size_t so = (size_t)B * 3;
  float o0n = op[0], o1n = op[1], o2n = op[2];
  float cxn = *cp;

  for (int t = 0; t < T; ++t) {
    const float o0 = o0n, o1 = o1n, o2 = o2n, cx = cxn;
    if (t + 1 < T) {                       // prefetch next step's inputs
      op += so; cp += B;
      o0n = op[0]; o1n = op[1]; o2n = op[2]; cxn = *cp;
    }

    // --- Kenyon update (own k-rows) + packed kc_value/apl partial sums ---
    float psum = 0.f;
    v2f p2[5];
    #pragma unroll
    for (int h = 0; h < 5; ++h) p2[h] = (v2f)(0.f);

    #pragma unroll
    for (int i = 0; i < 4; ++i) {
      if (i < 3 || has4) {
        const float base = knb[i] - apl;                 // fold bias-apl into fma chain
        float pv = fmaf(pw0[i], o0, fmaf(pw1[i], o1, fmaf(pw2[i], o2, base)));
        float r  = fmaxf(pv, 0.f);
        float kn = 0.5f * (kcn[i] + r);                  // dt_tau = 0.5
        kcn[i] = kn;
        lkc[i] = fmaf(ALPHA, kn - lkc[i], lkc[i]);       // low_kc_n (new kc_n)
        psum = fmaf(kn, aw[i], psum);
        #pragma unroll
        for (int h = 0; h < 5; ++h) p2[h] += kn * kcw[i][h];  // vs pre-update kc_w
      }
    }

    psum = rowsum16(psum);
    #pragma unroll
    for (int h = 0; h < 5; ++h) {
      p2[h].x = rowsum16(p2[h].x);
      p2[h].y = rowsum16(p2[h].y);
    }

    apl = 0.5f * apl + 0.5f * fmaxf(psum + aplb, 0.f);

    // select this lane's column value (kc_value[j])
    v2f rsel = p2[0];
    #pragma unroll
    for (int h = 1; h < 5; ++h) rsel = (jhalf == h) ? p2[h] : rsel;
    const float kcv = jodd ? rsel.y : rsel.x;

    // --- MBON (column j): dan_mod uses PREVIOUS dan (replicated dvec2) ---
    v2f s2 = dvec2[0] * mdw2[0];
    #pragma unroll
    for (int e = 1; e < 5; ++e) s2 += dvec2[e] * mdw2[e];
    const float s = s2.x + s2.y;
    const float dmod = 1.f / (1.f + __expf(-s));
    mbon_m = 0.5f * mbon_m + 0.5f * dmod * fmaxf(kcv + mb_, 0.f);

    // --- DAN: row-distributed matvec, replicated via rowsum (NO bpermute/LDS) ---
    // dp[m] = sum_j dan_j*ddw[j][m] + sum_j mbon_j*dmw[j][m] + cx*dcw[m] + dan_b[m]
    // lane j<10 contributes its rows with its OWN scalars; lane 10 contributes bias+ctx.
    const float du = isl10 ? cx  : dan_m;
    const float mu = isl10 ? 1.f : mbon_m;
    v2f c2[5];
    #pragma unroll
    for (int h = 0; h < 5; ++h) c2[h] = du * ddwr[h] + mu * dmwr[h];
    #pragma unroll
    for (int h = 0; h < 5; ++h) {
      c2[h].x = rowsum16(c2[h].x);
      c2[h].y = rowsum16(c2[h].y);
    }

    // extract this lane's dp_j to keep the scalar dan_m consistent
    v2f rs2 = c2[0];
    #pragma unroll
    for (int h = 1; h < 5; ++h) rs2 = (jhalf == h) ? c2[h] : rs2;
    const float dpj = jodd ? rs2.y : rs2.x;
    dan_m = 0.5f * dan_m + 0.5f * fmaxf(dpj, 0.f);

    // replicated dan / low_dan update (all 16 lanes hold the full vectors)
    #pragma unroll
    for (int h = 0; h < 5; ++h) {
      v2f dn;
      dn.x = fmaxf(c2[h].x, 0.f);
      dn.y = fmaxf(c2[h].y, 0.f);
      dvec2[h] = 0.5f * dvec2[h] + 0.5f * dn;
      ldv2[h] += ALPHA * (dvec2[h] - ldv2[h]);          // low_dan_n (new dan)
    }

    // --- decoder output ---
    const float q0 = rowsum16(mbon_m * dw0) + db0;
    const float q1 = rowsum16(mbon_m * dw1) + db1;
    if (j == 0) {
      float2 st; st.x = q0; st.y = q1;
      *reinterpret_cast<float2*>(out + ((size_t)t * B + b) * 2) = st;
    }

    // --- plasticity (packed): kc_w' = 0.75*kc_w + Bq ; Bq' = Bq + 0.125*(kcn*ldv - lkc*dv)
    #pragma unroll
    for (int i = 0; i < 4; ++i) {
      if (i < 3 || has4) {
        const float kh  =  0.125f * kcn[i];    // 0.25 * DT * kc_n
        const float nlh = -0.125f * lkc[i];    // -0.25 * DT * low_kc_n
        #pragma unroll
        for (int h = 0; h < 5; ++h) {
          const v2f w = wct[i][h];
          kcw[i][h] = 0.75f * kcw[i][h] + w;               // uses Bq BEFORE syn
          wct[i][h] = w + kh * ldv2[h] + nlh * dvec2[h];   // Bq_n
        }
      }
    }
  }
}

extern "C" void kernel_launch(void* const* d_in, const int* in_sizes, int n_in,
                              void* d_out, int out_size, void* d_ws, size_t ws_size,
                              hipStream_t stream) {
  const float* odor   = (const float*)d_in[0];
  const float* ctx    = (const float*)d_in[1];
  const float* pn_w   = (const float*)d_in[2];
  const float* kn_b   = (const float*)d_in[3];
  const float* apl_w  = (const float*)d_in[4];
  const float* apl_b  = (const float*)d_in[5];
  const float* mdw    = (const float*)d_in[6];
  const float* mbon_b = (const float*)d_in[7];
  const float* dmw    = (const float*)d_in[8];
  const float* ddw    = (const float*)d_in[9];
  const float* dcw    = (const float*)d_in[10];
  const float* dan_b  = (const float*)d_in[11];
  const float* decW   = (const float*)d_in[12];
  const float* decb   = (const float*)d_in[13];
  const float* kcw0   = (const float*)d_in[14];
  const float* wact0  = (const float*)d_in[15];
  float* out = (float*)d_out;

  const int B = in_sizes[14] / (KN * NM);   // kc_weight0 is [B,50,10]
  const int T = in_sizes[0] / (B * 3);      // odor is [T,B,3]

  const int batches_per_block = 256 / LPB;  // 16
  dim3 grid((B + batches_per_block - 1) / batches_per_block);
  dim3 block(256);
  hipLaunchKernelGGL(fly_kernel, grid, block, 0, stream,
                     odor, ctx, pn_w, kn_b, apl_w, apl_b,
                     mdw, mbon_b, dmw, ddw, dcw, dan_b,
                     decW, decb, kcw0, wact0, out, B, T);
}

// Round 6
// 822.530 us; speedup vs baseline: 1.1778x; 1.1778x over previous
//
#include <hip/hip_runtime.h>

#define KN  50
#define NM  10          // MBON == DAN == 10
#define LPB 16          // lanes per batch element

typedef float v2f __attribute__((ext_vector_type(2)));

// mov_dpp(old=0,bound_ctrl=1) + fadd; GCNDPPCombine fuses into v_add_f32_dpp (1 inst)
template <int CTRL>
__device__ __forceinline__ float dpp_add(float x) {
  return x + __int_as_float(
      __builtin_amdgcn_update_dpp(0, __float_as_int(x), CTRL, 0xF, 0xF, true));
}

__device__ __forceinline__ float rowsum16(float x) {
  x = dpp_add<0x121>(x);   // row_ror:1
  x = dpp_add<0x122>(x);   // row_ror:2
  x = dpp_add<0x124>(x);   // row_ror:4
  x = dpp_add<0x128>(x);   // row_ror:8
  return x;
}

__device__ __forceinline__ float bcast(int idx4, float x) {
  return __int_as_float(__builtin_amdgcn_ds_bpermute(idx4, __float_as_int(x)));
}

extern "C" __global__ void __launch_bounds__(256)
// (2,2) is the proven floor: any budget <256 regs (rounds 1/3/4) spills the persistent
// plastic state (VGPR->64, FETCH 10-20 GB, 5-7x slow). Do not raise occupancy.
// Round-2/5 lesson: LDS round-trips and rowsum-replication on the mbon->dan recurrence
// REGRESS; ds_bpermute broadcasts (this structure) are the best-latency form found.
__attribute__((amdgpu_waves_per_eu(2, 2)))
fly_kernel(const float* __restrict__ odor,    // [T,B,3]
           const float* __restrict__ ctxp,    // [T,B,1]
           const float* __restrict__ pn_w,    // [B,3,KN]
           const float* __restrict__ kn_b,    // [KN]
           const float* __restrict__ apl_w,   // [KN,1]
           const float* __restrict__ apl_b,   // [1]
           const float* __restrict__ mdw_g,   // mbon_dan_weight [DAN,MBON]
           const float* __restrict__ mbon_b,  // [MBON]
           const float* __restrict__ dmw_g,   // dan_mbon_weight [MBON,DAN]
           const float* __restrict__ ddw_g,   // dan_dan_weight [DAN,DAN]
           const float* __restrict__ dcw_g,   // dan_context_weight [1,DAN]
           const float* __restrict__ dan_b,   // [DAN]
           const float* __restrict__ decW,    // [2,MBON]
           const float* __restrict__ decb,    // [2]
           const float* __restrict__ kcw0,    // [B,KN,MBON]
           const float* __restrict__ wact0,   // [B,KN,MBON]
           float* __restrict__ out,           // [T,B,2]
           int B, int T)
{
  const int tid   = threadIdx.x;
  const int j     = tid & (LPB - 1);
  const int jhalf = j >> 1;
  const int jodd  = j & 1;
  const int b     = blockIdx.x * (256 / LPB) + (tid >> 4);
  if (b >= B) return;

  const int base4 = (tid & 48) << 2;          // byte index of lane 0 of this 16-lane group
  const bool has4 = (j + 48) < KN;            // lanes 0,1 own a 4th k-row (LOAD guard only)

  // ---- persistent plastic state + per-batch weights (VGPRs) ----
  // wct holds Bq = 0.25*wact (exact pow2 scale) -> kc_w decay is one pk_fma per v2f.
  v2f   kcw[4][5], wct[4][5];                 // rows j,16+j,32+j,48+j  x  10 cols (packed)
  float pw0[4], pw1[4], pw2[4], knb[4], aw[4];
  float kcn[4] = {0.f,0.f,0.f,0.f}, lkc[4] = {0.f,0.f,0.f,0.f};

  #pragma unroll
  for (int i = 0; i < 4; ++i) {
    const int k = j + 16 * i;
    if (i < 3 || has4) {
      const v2f* a = reinterpret_cast<const v2f*>(kcw0  + ((size_t)b * KN + k) * NM);
      const v2f* w = reinterpret_cast<const v2f*>(wact0 + ((size_t)b * KN + k) * NM);
      #pragma unroll
      for (int h = 0; h < 5; ++h) { kcw[i][h] = a[h]; wct[i][h] = 0.25f * w[h]; }
      pw0[i] = pn_w[((size_t)b * 3 + 0) * KN + k];
      pw1[i] = pn_w[((size_t)b * 3 + 1) * KN + k];
      pw2[i] = pn_w[((size_t)b * 3 + 2) * KN + k];
      knb[i] = kn_b[k];
      aw[i]  = apl_w[k];
    } else {
      // zero-padded: the step loop runs these rows BRANCHLESS and they stay exactly 0
      // (base = 0 - apl <= 0 since apl >= 0 invariantly -> relu = 0; zero weights
      //  propagate zeros through psum/p2/plasticity).
      #pragma unroll
      for (int h = 0; h < 5; ++h) { kcw[i][h] = (v2f)(0.f); wct[i][h] = (v2f)(0.f); }
      pw0[i] = pw1[i] = pw2[i] = 0.f; knb[i] = 0.f; aw[i] = 0.f;
    }
  }

  // ---- per-column (m == j) small weights; lanes j>=10 hold zeros ----
  v2f   mdw2[5], ddw2[5];
  float dmw[NM];
  float cw = 0.f, db_ = 0.f, mb_ = 0.f, dw0 = 0.f, dw1 = 0.f;
  #pragma unroll
  for (int h = 0; h < 5; ++h) { mdw2[h] = (v2f)(0.f); ddw2[h] = (v2f)(0.f); }
  #pragma unroll
  for (int m = 0; m < NM; ++m) dmw[m] = 0.f;
  if (j < NM) {
    #pragma unroll
    for (int h = 0; h < 5; ++h) {
      mdw2[h].x = mdw_g[(2*h)   * NM + j];  mdw2[h].y = mdw_g[(2*h+1) * NM + j];
      ddw2[h].x = ddw_g[(2*h)   * NM + j];  ddw2[h].y = ddw_g[(2*h+1) * NM + j];
    }
    #pragma unroll
    for (int m = 0; m < NM; ++m) dmw[m] = dmw_g[m * NM + j];
    cw  = dcw_g[j];
    db_ = dan_b[j];
    mb_ = mbon_b[j];
    dw0 = decW[j];
    dw1 = decW[NM + j];
  }
  const float aplb = apl_b[0];
  const float db0 = decb[0], db1 = decb[1];

  const float ALPHA = (float)(0.5 / 5.5);     // DT/(DT+RC)

  // ---- recurrent small state ----
  float apl = 0.f, mbon_m = 0.f, dan_m = 0.f;
  v2f dvec2[5], ldv2[5];
  #pragma unroll
  for (int h = 0; h < 5; ++h) { dvec2[h] = (v2f)(0.f); ldv2[h] = (v2f)(0.f); }

  // input pointers (strength-reduced); prefetch t=0
  const float* op = odor + (size_t)b * 3;
  const float* cp = ctxp + b;
  const size_t so = (size_t)B * 3;
  float o0n = op[0], o1n = op[1], o2n = op[2];
  float cxn = *cp;

  for (int t = 0; t < T; ++t) {
    const float o0 = o0n, o1 = o1n, o2 = o2n, cx = cxn;
    if (t + 1 < T) {                       // prefetch next step's inputs (uniform branch)
      op += so; cp += B;
      o0n = op[0]; o1n = op[1]; o2n = op[2]; cxn = *cp;
    }

    // --- Kenyon update (own k-rows, BRANCHLESS) + packed kc_value/apl partials ---
    float psum = 0.f;
    v2f p2[5];
    #pragma unroll
    for (int h = 0; h < 5; ++h) p2[h] = (v2f)(0.f);

    #pragma unroll
    for (int i = 0; i < 4; ++i) {
      const float base = knb[i] - apl;                 // fold bias-apl into fma chain
      float pv = fmaf(pw0[i], o0, fmaf(pw1[i], o1, fmaf(pw2[i], o2, base)));
      float kn = 0.5f * (kcn[i] + fmaxf(pv, 0.f));     // dt_tau = 0.5
      kcn[i] = kn;
      lkc[i] = fmaf(ALPHA, kn - lkc[i], lkc[i]);       // low_kc_n (new kc_n)
      psum = fmaf(kn, aw[i], psum);
      #pragma unroll
      for (int h = 0; h < 5; ++h) p2[h] += kn * kcw[i][h];  // vs pre-decay kc_w (W_t)
    }

    // --- kc_w decay hoisted here: W_{t+1} = 0.75*W_t + Bq_{t-1->t}. Only needs
    // pre-syn wct and post-p2 kcw -> 20 pk_fma of independent work that the
    // scheduler can interleave with the 44-DPP rowsum block below.
    #pragma unroll
    for (int i = 0; i < 4; ++i)
      #pragma unroll
      for (int h = 0; h < 5; ++h) kcw[i][h] = 0.75f * kcw[i][h] + wct[i][h];

    psum = rowsum16(psum);
    #pragma unroll
    for (int h = 0; h < 5; ++h) {
      p2[h].x = rowsum16(p2[h].x);
      p2[h].y = rowsum16(p2[h].y);
    }

    apl = 0.5f * apl + 0.5f * fmaxf(psum + aplb, 0.f);

    // select this lane's column value
    v2f rsel = p2[0];
    #pragma unroll
    for (int h = 1; h < 5; ++h) rsel = (jhalf == h) ? p2[h] : rsel;
    const float kcv = jodd ? rsel.y : rsel.x;

    // --- MBON (column j): dan_mod uses PREVIOUS dan ---
    v2f s2 = dvec2[0] * mdw2[0];
    #pragma unroll
    for (int e = 1; e < 5; ++e) s2 += dvec2[e] * mdw2[e];
    const float s = s2.x + s2.y;
    const float dmod = 1.f / (1.f + __expf(-s));
    mbon_m = 0.5f * mbon_m + 0.5f * dmod * fmaxf(kcv + mb_, 0.f);

    // --- DAN (column j): previous dan + new mbon (bpermute broadcast, split chain) ---
    v2f dp2 = dvec2[0] * ddw2[0];
    #pragma unroll
    for (int e = 1; e < 5; ++e) dp2 += dvec2[e] * ddw2[e];
    float dpA = dp2.x + fmaf(cx, cw, db_);
    float dpB = dp2.y;
    #pragma unroll
    for (int m = 0; m < NM; m += 2) {                 // two accumulators halve the
      dpA = fmaf(bcast(base4 + 4*m,     mbon_m), dmw[m],     dpA);   // serial fma chain
      dpB = fmaf(bcast(base4 + 4*m + 4, mbon_m), dmw[m + 1], dpB);
    }
    dan_m = 0.5f * dan_m + 0.5f * fmaxf(dpA + dpB, 0.f);

    // broadcast new dan to all 16 lanes; update low_dan
    #pragma unroll
    for (int e = 0; e < 5; ++e) {
      dvec2[e].x = bcast(base4 + 8 * e,     dan_m);
      dvec2[e].y = bcast(base4 + 8 * e + 4, dan_m);
      ldv2[e] += ALPHA * (dvec2[e] - ldv2[e]);        // low_dan_n (new dan)
    }

    // --- decoder output ---
    const float q0 = rowsum16(mbon_m * dw0) + db0;
    const float q1 = rowsum16(mbon_m * dw1) + db1;
    if (j == 0) {
      float2 st; st.x = q0; st.y = q1;
      *reinterpret_cast<float2*>(out + ((size_t)t * B + b) * 2) = st;
    }

    // --- plasticity trace (BRANCHLESS): Bq' = Bq + 0.125*(kcn*ldv - lkc*dv) ---
    #pragma unroll
    for (int i = 0; i < 4; ++i) {
      const float kh  =  0.125f * kcn[i];    // 0.25 * DT * kc_n
      const float nlh = -0.125f * lkc[i];    // -0.25 * DT * low_kc_n
      #pragma unroll
      for (int h = 0; h < 5; ++h)
        wct[i][h] = wct[i][h] + kh * ldv2[h] + nlh * dvec2[h];   // Bq_n
    }
  }
}

extern "C" void kernel_launch(void* const* d_in, const int* in_sizes, int n_in,
                              void* d_out, int out_size, void* d_ws, size_t ws_size,
                              hipStream_t stream) {
  const float* odor   = (const float*)d_in[0];
  const float* ctx    = (const float*)d_in[1];
  const float* pn_w   = (const float*)d_in[2];
  const float* kn_b   = (const float*)d_in[3];
  const float* apl_w  = (const float*)d_in[4];
  const float* apl_b  = (const float*)d_in[5];
  const float* mdw    = (const float*)d_in[6];
  const float* mbon_b = (const float*)d_in[7];
  const float* dmw    = (const float*)d_in[8];
  const float* ddw    = (const float*)d_in[9];
  const float* dcw    = (const float*)d_in[10];
  const float* dan_b  = (const float*)d_in[11];
  const float* decW   = (const float*)d_in[12];
  const float* decb   = (const float*)d_in[13];
  const float* kcw0   = (const float*)d_in[14];
  const float* wact0  = (const float*)d_in[15];
  float* out = (float*)d_out;

  const int B = in_sizes[14] / (KN * NM);   // kc_weight0 is [B,50,10]
  const int T = in_sizes[0] / (B * 3);      // odor is [T,B,3]

  const int batches_per_block = 256 / LPB;  // 16
  dim3 grid((B + batches_per_block - 1) / batches_per_block);
  dim3 block(256);
  hipLaunchKernelGGL(fly_kernel, grid, block, 0, stream,
                     odor, ctx, pn_w, kn_b, apl_w, apl_b,
                     mdw, mbon_b, dmw, ddw, dcw, dan_b,
                     decW, decb, kcw0, wact0, out, B, T);
}

// Round 7
// 769.036 us; speedup vs baseline: 1.2597x; 1.0696x over previous
//
#include <hip/hip_runtime.h>

#define KN  50
#define NM  10          // MBON == DAN == 10
#define LPB 16          // lanes per batch element

typedef float v2f __attribute__((ext_vector_type(2)));

// mov_dpp(old=0,bound_ctrl=1) + fadd; GCNDPPCombine fuses into v_add_f32_dpp (1 inst)
template <int CTRL>
__device__ __forceinline__ float dpp_add(float x) {
  return x + __int_as_float(
      __builtin_amdgcn_update_dpp(0, __float_as_int(x), CTRL, 0xF, 0xF, true));
}

__device__ __forceinline__ float rowsum16(float x) {
  x = dpp_add<0x121>(x);   // row_ror:1
  x = dpp_add<0x122>(x);   // row_ror:2
  x = dpp_add<0x124>(x);   // row_ror:4
  x = dpp_add<0x128>(x);   // row_ror:8
  return x;
}

__device__ __forceinline__ float bcast(int idx4, float x) {
  return __int_as_float(__builtin_amdgcn_ds_bpermute(idx4, __float_as_int(x)));
}

extern "C" __global__ void __launch_bounds__(256)
// (2,2) is the proven floor: any budget <256 regs (rounds 1/3/4) spills the persistent
// plastic state (VGPR->64, FETCH 10-20 GB, 5-7x slow). Occupancy is hardware-capped here.
// Rounds 0/6 both pin at 757us with 83%/72% VALUBusy -> latency-bound at the crossover;
// this version software-rotates the loop so the dan-broadcast + exp latencies span the
// loop boundary under ~55 insts of independent cover.
__attribute__((amdgpu_waves_per_eu(2, 2)))
fly_kernel(const float* __restrict__ odor,    // [T,B,3]
           const float* __restrict__ ctxp,    // [T,B,1]
           const float* __restrict__ pn_w,    // [B,3,KN]
           const float* __restrict__ kn_b,    // [KN]
           const float* __restrict__ apl_w,   // [KN,1]
           const float* __restrict__ apl_b,   // [1]
           const float* __restrict__ mdw_g,   // mbon_dan_weight [DAN,MBON]
           const float* __restrict__ mbon_b,  // [MBON]
           const float* __restrict__ dmw_g,   // dan_mbon_weight [MBON,DAN]
           const float* __restrict__ ddw_g,   // dan_dan_weight [DAN,DAN]
           const float* __restrict__ dcw_g,   // dan_context_weight [1,DAN]
           const float* __restrict__ dan_b,   // [DAN]
           const float* __restrict__ decW,    // [2,MBON]
           const float* __restrict__ decb,    // [2]
           const float* __restrict__ kcw0,    // [B,KN,MBON]
           const float* __restrict__ wact0,   // [B,KN,MBON]
           float* __restrict__ out,           // [T,B,2]
           int B, int T)
{
  const int tid   = threadIdx.x;
  const int j     = tid & (LPB - 1);
  const int jhalf = j >> 1;
  const int jodd  = j & 1;
  const int b     = blockIdx.x * (256 / LPB) + (tid >> 4);
  if (b >= B) return;

  const int base4 = (tid & 48) << 2;          // byte index of lane 0 of this 16-lane group
  const bool has4 = (j + 48) < KN;            // lanes 0,1 own a 4th k-row (LOAD guard only)

  // ---- persistent plastic state + per-batch weights (VGPRs) ----
  // wct holds Bq = 0.25*wact (exact pow2 scale) -> kc_w decay is one pk_fma per v2f.
  v2f   kcw[4][5], wct[4][5];                 // rows j,16+j,32+j,48+j  x  10 cols (packed)
  float pw0[4], pw1[4], pw2[4], knb[4], aw[4];
  float kcn[4] = {0.f,0.f,0.f,0.f}, lkc[4] = {0.f,0.f,0.f,0.f};

  #pragma unroll
  for (int i = 0; i < 4; ++i) {
    const int k = j + 16 * i;
    if (i < 3 || has4) {
      const v2f* a = reinterpret_cast<const v2f*>(kcw0  + ((size_t)b * KN + k) * NM);
      const v2f* w = reinterpret_cast<const v2f*>(wact0 + ((size_t)b * KN + k) * NM);
      #pragma unroll
      for (int h = 0; h < 5; ++h) { kcw[i][h] = a[h]; wct[i][h] = 0.25f * w[h]; }
      pw0[i] = pn_w[((size_t)b * 3 + 0) * KN + k];
      pw1[i] = pn_w[((size_t)b * 3 + 1) * KN + k];
      pw2[i] = pn_w[((size_t)b * 3 + 2) * KN + k];
      knb[i] = kn_b[k];
      aw[i]  = apl_w[k];
    } else {
      // zero-padded rows run branchless and stay exactly 0 (apl >= 0 -> relu(-apl)=0;
      // zero weights propagate zeros through psum/p2/plasticity).
      #pragma unroll
      for (int h = 0; h < 5; ++h) { kcw[i][h] = (v2f)(0.f); wct[i][h] = (v2f)(0.f); }
      pw0[i] = pw1[i] = pw2[i] = 0.f; knb[i] = 0.f; aw[i] = 0.f;
    }
  }

  // ---- per-column (m == j) small weights; lanes j>=10 hold zeros ----
  v2f   mdw2[5], ddw2[5];
  float dmw[NM];
  float cw = 0.f, db_ = 0.f, mb_ = 0.f, dw0 = 0.f, dw1 = 0.f;
  #pragma unroll
  for (int h = 0; h < 5; ++h) { mdw2[h] = (v2f)(0.f); ddw2[h] = (v2f)(0.f); }
  #pragma unroll
  for (int m = 0; m < NM; ++m) dmw[m] = 0.f;
  if (j < NM) {
    #pragma unroll
    for (int h = 0; h < 5; ++h) {
      mdw2[h].x = mdw_g[(2*h)   * NM + j];  mdw2[h].y = mdw_g[(2*h+1) * NM + j];
      ddw2[h].x = ddw_g[(2*h)   * NM + j];  ddw2[h].y = ddw_g[(2*h+1) * NM + j];
    }
    #pragma unroll
    for (int m = 0; m < NM; ++m) dmw[m] = dmw_g[m * NM + j];
    cw  = dcw_g[j];
    db_ = dan_b[j];
    mb_ = mbon_b[j];
    dw0 = decW[j];
    dw1 = decW[NM + j];
  }
  const float aplb = apl_b[0];
  const float db0 = decb[0], db1 = decb[1];

  const float ALPHA = (float)(0.5 / 5.5);     // DT/(DT+RC)

  // ---- recurrent small state ----
  float apl = 0.f, mbon_m = 0.f, dan_m = 0.f;
  v2f dvec2[5], ldv2[5];
  #pragma unroll
  for (int h = 0; h < 5; ++h) { dvec2[h] = (v2f)(0.f); ldv2[h] = (v2f)(0.f); }

  // input pointers (strength-reduced); prefetch t=0
  const float* op = odor + (size_t)b * 3;
  const float* cp = ctxp + b;
  const size_t so = (size_t)B * 3;
  float o0n = op[0], o1n = op[1], o2n = op[2];
  float cxn = *cp;

  for (int t = 0; t < T; ++t) {
    const float o0 = o0n, o1 = o1n, o2 = o2n, cx = cxn;
    if (t + 1 < T) {                       // prefetch next step's inputs (uniform branch)
      op += so; cp += B;
      o0n = op[0]; o1n = op[1]; o2n = op[2]; cxn = *cp;
    }

    // --- Phase 1: KC scalar update (independent of dvec; covers the in-flight
    //     dan-broadcast bpermutes issued at the END of step t-1).
    //     Save pre-update kcn/lkc (scaled) for the DEFERRED trace of step t-1.
    float ko[4], lo[4];
    float psum = 0.f;
    #pragma unroll
    for (int i = 0; i < 4; ++i) {
      ko[i] =  0.125f * kcn[i];                        // 0.25*DT * kc_n(t-1)
      lo[i] = -0.125f * lkc[i];                        // -0.25*DT * low_kc_n(t-1)
      const float base = knb[i] - apl;                 // fold bias-apl into fma chain
      float pv = fmaf(pw0[i], o0, fmaf(pw1[i], o1, fmaf(pw2[i], o2, base)));
      float kn = 0.5f * (kcn[i] + fmaxf(pv, 0.f));     // dt_tau = 0.5
      kcn[i] = kn;
      lkc[i] = fmaf(ALPHA, kn - lkc[i], lkc[i]);       // low_kc_n (new kc_n)
      psum = fmaf(kn, aw[i], psum);
    }

    // --- Phase 2: kc_w decay  W_t = 0.75*W_{t-1} + Bq_{t-1}  (no dvec dependency).
    //     Skipped at t=0 so p2 uses kcw0 exactly (uniform branch, ~2 SALU).
    if (t) {
      #pragma unroll
      for (int i = 0; i < 4; ++i)
        #pragma unroll
        for (int h = 0; h < 5; ++h) kcw[i][h] = 0.75f * kcw[i][h] + wct[i][h];
    }

    // --- Phase 3: dvec_{t-1}-dependent block (broadcast has had ~55 insts to land).
    // low_dan update for step t-1 (must precede trace: syn uses low_dan_n).
    #pragma unroll
    for (int e = 0; e < 5; ++e) ldv2[e] += ALPHA * (dvec2[e] - ldv2[e]);
    // mbon gate for THIS step (uses prev dan) - exp issues ~100 insts before use.
    v2f s2 = dvec2[0] * mdw2[0];
    #pragma unroll
    for (int e = 1; e < 5; ++e) s2 += dvec2[e] * mdw2[e];
    const float dmod = 1.f / (1.f + __expf(-(s2.x + s2.y)));
    // dan self-term for THIS step (uses prev dan).
    v2f dp2 = dvec2[0] * ddw2[0];
    #pragma unroll
    for (int e = 1; e < 5; ++e) dp2 += dvec2[e] * ddw2[e];
    // DEFERRED plasticity trace of step t-1: Bq += 0.125*(kcn*ldv - lkc*dvec).
    // At t=0: ko=lo=0 -> adds exact zeros.
    #pragma unroll
    for (int i = 0; i < 4; ++i) {
      #pragma unroll
      for (int h = 0; h < 5; ++h)
        wct[i][h] = wct[i][h] + ko[i] * ldv2[h] + lo[i] * dvec2[h];
    }

    // --- Phase 4: packed kc_value partials with new kn and W_t ---
    v2f p2[5];
    #pragma unroll
    for (int h = 0; h < 5; ++h) p2[h] = (v2f)(0.f);
    #pragma unroll
    for (int i = 0; i < 4; ++i) {
      #pragma unroll
      for (int h = 0; h < 5; ++h) p2[h] += kcn[i] * kcw[i][h];
    }

    // --- Phase 5: rowsums + apl + kcv select ---
    psum = rowsum16(psum);
    #pragma unroll
    for (int h = 0; h < 5; ++h) {
      p2[h].x = rowsum16(p2[h].x);
      p2[h].y = rowsum16(p2[h].y);
    }
    apl = 0.5f * apl + 0.5f * fmaxf(psum + aplb, 0.f);
    v2f rsel = p2[0];
    #pragma unroll
    for (int h = 1; h < 5; ++h) rsel = (jhalf == h) ? p2[h] : rsel;
    const float kcv = jodd ? rsel.y : rsel.x;

    // --- Phase 6: MBON (dmod precomputed) ---
    mbon_m = 0.5f * mbon_m + 0.5f * dmod * fmaxf(kcv + mb_, 0.f);

    // --- Phase 7: batch-issue mbon broadcasts; decoder rowsums fill the latency ---
    float bm[NM];
    #pragma unroll
    for (int m = 0; m < NM; ++m) bm[m] = bcast(base4 + 4 * m, mbon_m);
    const float q0 = rowsum16(mbon_m * dw0) + db0;
    const float q1 = rowsum16(mbon_m * dw1) + db1;

    // --- Phase 8: DAN accumulate (split chain) ---
    float dpA = dp2.x + fmaf(cx, cw, db_);
    float dpB = dp2.y;
    #pragma unroll
    for (int m = 0; m < NM; m += 2) {
      dpA = fmaf(bm[m],     dmw[m],     dpA);
      dpB = fmaf(bm[m + 1], dmw[m + 1], dpB);
    }
    dan_m = 0.5f * dan_m + 0.5f * fmaxf(dpA + dpB, 0.f);

    // --- Phase 9: issue dan broadcast; consumed at Phase 3 of step t+1 ---
    #pragma unroll
    for (int e = 0; e < 5; ++e) {
      dvec2[e].x = bcast(base4 + 8 * e,     dan_m);
      dvec2[e].y = bcast(base4 + 8 * e + 4, dan_m);
    }

    // --- Phase 10: store (independent; adds cover for the dan broadcast) ---
    if (j == 0) {
      float2 st; st.x = q0; st.y = q1;
      *reinterpret_cast<float2*>(out + ((size_t)t * B + b) * 2) = st;
    }
  }
}

extern "C" void kernel_launch(void* const* d_in, const int* in_sizes, int n_in,
                              void* d_out, int out_size, void* d_ws, size_t ws_size,
                              hipStream_t stream) {
  const float* odor   = (const float*)d_in[0];
  const float* ctx    = (const float*)d_in[1];
  const float* pn_w   = (const float*)d_in[2];
  const float* kn_b   = (const float*)d_in[3];
  const float* apl_w  = (const float*)d_in[4];
  const float* apl_b  = (const float*)d_in[5];
  const float* mdw    = (const float*)d_in[6];
  const float* mbon_b = (const float*)d_in[7];
  const float* dmw    = (const float*)d_in[8];
  const float* ddw    = (const float*)d_in[9];
  const float* dcw    = (const float*)d_in[10];
  const float* dan_b  = (const float*)d_in[11];
  const float* decW   = (const float*)d_in[12];
  const float* decb   = (const float*)d_in[13];
  const float* kcw0   = (const float*)d_in[14];
  const float* wact0  = (const float*)d_in[15];
  float* out = (float*)d_out;

  const int B = in_sizes[14] / (KN * NM);   // kc_weight0 is [B,50,10]
  const int T = in_sizes[0] / (B * 3);      // odor is [T,B,3]

  const int batches_per_block = 256 / LPB;  // 16
  dim3 grid((B + batches_per_block - 1) / batches_per_block);
  dim3 block(256);
  hipLaunchKernelGGL(fly_kernel, grid, block, 0, stream,
                     odor, ctx, pn_w, kn_b, apl_w, apl_b,
                     mdw, mbon_b, dmw, ddw, dcw, dan_b,
                     decW, decb, kcw0, wact0, out, B, T);
}

// Round 8
// 751.690 us; speedup vs baseline: 1.2888x; 1.0231x over previous
//
#include <hip/hip_runtime.h>

#define KN  50
#define NM  10          // MBON == DAN == 10
#define LPB 16          // lanes per batch element

typedef float v2f __attribute__((ext_vector_type(2)));

// mov_dpp(old=0,bound_ctrl=1) + fadd; GCNDPPCombine fuses into v_add_f32_dpp (1 inst)
template <int CTRL>
__device__ __forceinline__ float dpp_add(float x) {
  return x + __int_as_float(
      __builtin_amdgcn_update_dpp(0, __float_as_int(x), CTRL, 0xF, 0xF, true));
}

__device__ __forceinline__ float rowsum16(float x) {
  x = dpp_add<0x121>(x);   // row_ror:1
  x = dpp_add<0x122>(x);   // row_ror:2
  x = dpp_add<0x124>(x);   // row_ror:4
  x = dpp_add<0x128>(x);   // row_ror:8
  return x;
}

__device__ __forceinline__ float bcast(int idx4, float x) {
  return __int_as_float(__builtin_amdgcn_ds_bpermute(idx4, __float_as_int(x)));
}

extern "C" __global__ void __launch_bounds__(256)
// (2,2) is the proven floor: any budget <256 regs (rounds 1/3/4) spills the persistent
// plastic state (VGPR->64, FETCH 10-20 GB, 5-7x slow). Occupancy is hardware-capped.
// Round-7 rotation (+8.5%) proved latency-cover is the converting lever. This round:
// exact pow2 scaled dan-space (free ko/lo saves), v2f-packed KC phase, and the
// plasticity trace moved to cover the mbon-broadcast latency.
__attribute__((amdgpu_waves_per_eu(2, 2)))
fly_kernel(const float* __restrict__ odor,    // [T,B,3]
           const float* __restrict__ ctxp,    // [T,B,1]
           const float* __restrict__ pn_w,    // [B,3,KN]
           const float* __restrict__ kn_b,    // [KN]
           const float* __restrict__ apl_w,   // [KN,1]
           const float* __restrict__ apl_b,   // [1]
           const float* __restrict__ mdw_g,   // mbon_dan_weight [DAN,MBON]
           const float* __restrict__ mbon_b,  // [MBON]
           const float* __restrict__ dmw_g,   // dan_mbon_weight [MBON,DAN]
           const float* __restrict__ ddw_g,   // dan_dan_weight [DAN,DAN]
           const float* __restrict__ dcw_g,   // dan_context_weight [1,DAN]
           const float* __restrict__ dan_b,   // [DAN]
           const float* __restrict__ decW,    // [2,MBON]
           const float* __restrict__ decb,    // [2]
           const float* __restrict__ kcw0,    // [B,KN,MBON]
           const float* __restrict__ wact0,   // [B,KN,MBON]
           float* __restrict__ out,           // [T,B,2]
           int B, int T)
{
  const int tid   = threadIdx.x;
  const int j     = tid & (LPB - 1);
  const int jhalf = j >> 1;
  const int jodd  = j & 1;
  const int b     = blockIdx.x * (256 / LPB) + (tid >> 4);
  if (b >= B) return;

  const int base4 = (tid & 48) << 2;          // byte index of lane 0 of this 16-lane group
  const bool has4 = (j + 48) < KN;            // lanes 0,1 own a 4th k-row (LOAD guard only)

  // ---- persistent plastic state + per-batch weights (VGPRs) ----
  // wct holds Bq = 0.25*wact (exact pow2) -> kc_w decay is one pk_fma per v2f.
  v2f   kcw[4][5], wct[4][5];                 // rows j,16+j,32+j,48+j  x  10 cols (packed)
  float pw0s[4], pw1s[4], pw2s[4], knbs[4], aws[4];

  #pragma unroll
  for (int i = 0; i < 4; ++i) {
    const int k = j + 16 * i;
    if (i < 3 || has4) {
      const v2f* a = reinterpret_cast<const v2f*>(kcw0  + ((size_t)b * KN + k) * NM);
      const v2f* w = reinterpret_cast<const v2f*>(wact0 + ((size_t)b * KN + k) * NM);
      #pragma unroll
      for (int h = 0; h < 5; ++h) { kcw[i][h] = a[h]; wct[i][h] = 0.25f * w[h]; }
      pw0s[i] = pn_w[((size_t)b * 3 + 0) * KN + k];
      pw1s[i] = pn_w[((size_t)b * 3 + 1) * KN + k];
      pw2s[i] = pn_w[((size_t)b * 3 + 2) * KN + k];
      knbs[i] = kn_b[k];
      aws[i]  = apl_w[k];
    } else {
      // zero-padded rows run branchless and stay exactly 0 (apl >= 0 -> relu(-apl)=0;
      // zero weights propagate zeros through psum/p2/plasticity).
      #pragma unroll
      for (int h = 0; h < 5; ++h) { kcw[i][h] = (v2f)(0.f); wct[i][h] = (v2f)(0.f); }
      pw0s[i] = pw1s[i] = pw2s[i] = 0.f; knbs[i] = 0.f; aws[i] = 0.f;
    }
  }

  // pack KC per-row constants into v2f pairs: pair p = rows (2p, 2p+1) i.e. {j+32p, j+32p+16}
  v2f pwA[2], pwB[2], pwC[2], knb2[2], aw2[2], kcn2[2], lkc2[2];
  #pragma unroll
  for (int p = 0; p < 2; ++p) {
    pwA[p].x = pw0s[2*p]; pwA[p].y = pw0s[2*p+1];
    pwB[p].x = pw1s[2*p]; pwB[p].y = pw1s[2*p+1];
    pwC[p].x = pw2s[2*p]; pwC[p].y = pw2s[2*p+1];
    knb2[p].x = knbs[2*p]; knb2[p].y = knbs[2*p+1];
    aw2[p].x = aws[2*p];  aw2[p].y = aws[2*p+1];
    kcn2[p] = (v2f)(0.f); lkc2[p] = (v2f)(0.f);
  }

  // ---- per-column (m == j) small weights; lanes j>=10 hold zeros ----
  // SCALED DAN SPACE: sdvec/sldv hold 0.125*(dan/low_dan); mdw/ddw pre-scaled x8
  // (exact pow2) so all dots are bit-identical. This makes the trace's ko/lo saves
  // free register copies instead of 8 muls/step.
  v2f   mdw2[5], ddw2[5];
  float dmw[NM];
  float cw = 0.f, db_ = 0.f, mb_ = 0.f, dw0 = 0.f, dw1 = 0.f;
  #pragma unroll
  for (int h = 0; h < 5; ++h) { mdw2[h] = (v2f)(0.f); ddw2[h] = (v2f)(0.f); }
  #pragma unroll
  for (int m = 0; m < NM; ++m) dmw[m] = 0.f;
  if (j < NM) {
    #pragma unroll
    for (int h = 0; h < 5; ++h) {
      mdw2[h].x = 8.f * mdw_g[(2*h)   * NM + j];  mdw2[h].y = 8.f * mdw_g[(2*h+1) * NM + j];
      ddw2[h].x = 8.f * ddw_g[(2*h)   * NM + j];  ddw2[h].y = 8.f * ddw_g[(2*h+1) * NM + j];
    }
    #pragma unroll
    for (int m = 0; m < NM; ++m) dmw[m] = dmw_g[m * NM + j];
    cw  = dcw_g[j];
    db_ = dan_b[j];
    mb_ = mbon_b[j];
    dw0 = decW[j];
    dw1 = decW[NM + j];
  }
  const float aplb = apl_b[0];
  const float db0 = decb[0], db1 = decb[1];

  const float ALPHA = (float)(0.5 / 5.5);     // DT/(DT+RC)

  // ---- recurrent small state ----
  float apl = 0.f, mbon_m = 0.f, dan_m = 0.f;
  v2f sdvec[5], sldv[5];                      // 0.125-scaled dan / low_dan (replic. via bpermute)
  #pragma unroll
  for (int h = 0; h < 5; ++h) { sdvec[h] = (v2f)(0.f); sldv[h] = (v2f)(0.f); }

  // input pointers (strength-reduced); prefetch t=0
  const float* op = odor + (size_t)b * 3;
  const float* cp = ctxp + b;
  const size_t so = (size_t)B * 3;
  float o0n = op[0], o1n = op[1], o2n = op[2];
  float cxn = *cp;

  for (int t = 0; t < T; ++t) {
    const float o0 = o0n, o1 = o1n, o2 = o2n, cx = cxn;
    if (t + 1 < T) {                       // prefetch next step's inputs (uniform branch)
      op += so; cp += B;
      o0n = op[0]; o1n = op[1]; o2n = op[2]; cxn = *cp;
    }

    // --- Phase 1: packed KC update (independent of sdvec; covers in-flight dan bcast).
    //     ko2/lo2 save pre-update kcn/lkc for the deferred trace -- FREE copies.
    v2f ko2[2], lo2[2];
    v2f psum2 = (v2f)(0.f);
    #pragma unroll
    for (int p = 0; p < 2; ++p) {
      ko2[p] = kcn2[p];
      lo2[p] = lkc2[p];
      v2f base2 = knb2[p] - apl;                       // pk, apl splat
      v2f pv = pwA[p] * o0 + (pwB[p] * o1 + (pwC[p] * o2 + base2));   // 3 pk_fma
      v2f r  = __builtin_elementwise_max(pv, (v2f)(0.f));
      v2f kn = (kcn2[p] + r) * 0.5f;                   // dt_tau = 0.5
      kcn2[p] = kn;
      lkc2[p] = lkc2[p] + ALPHA * (kn - lkc2[p]);      // low_kc_n
      psum2 = psum2 + kn * aw2[p];
    }
    float psum = psum2.x + psum2.y;

    // --- Phase 2: kc_w decay  W_t = 0.75*W_{t-1} + Bq  (pre-trace Bq; see invariant).
    //     Skipped at t=0 so p2 uses kcw0 exactly (uniform branch).
    if (t) {
      #pragma unroll
      for (int i = 0; i < 4; ++i)
        #pragma unroll
        for (int h = 0; h < 5; ++h) kcw[i][h] = 0.75f * kcw[i][h] + wct[i][h];
    }

    // --- Phase 3: sdvec-dependent dots (dan bcast has had ~50 insts to land) ---
    #pragma unroll
    for (int e = 0; e < 5; ++e) sldv[e] += ALPHA * (sdvec[e] - sldv[e]);  // scaled low_dan
    v2f s2 = sdvec[0] * mdw2[0];                       // mdw pre-scaled x8: exact
    #pragma unroll
    for (int e = 1; e < 5; ++e) s2 += sdvec[e] * mdw2[e];
    const float dmod = 1.f / (1.f + __expf(-(s2.x + s2.y)));
    v2f dp2 = sdvec[0] * ddw2[0];                      // ddw pre-scaled x8: exact
    #pragma unroll
    for (int e = 1; e < 5; ++e) dp2 += sdvec[e] * ddw2[e];

    // --- Phase 4: packed kc_value partials with new kn and W_t ---
    const float k0 = kcn2[0].x, k1 = kcn2[0].y, k2 = kcn2[1].x, k3 = kcn2[1].y;
    v2f p2[5];
    #pragma unroll
    for (int h = 0; h < 5; ++h)
      p2[h] = (k0 * kcw[0][h] + k1 * kcw[1][h]) + (k2 * kcw[2][h] + k3 * kcw[3][h]);

    // --- Phase 5: rowsums + apl + kcv select ---
    psum = rowsum16(psum);
    #pragma unroll
    for (int h = 0; h < 5; ++h) {
      p2[h].x = rowsum16(p2[h].x);
      p2[h].y = rowsum16(p2[h].y);
    }
    apl = 0.5f * apl + 0.5f * fmaxf(psum + aplb, 0.f);
    v2f rsel = p2[0];
    #pragma unroll
    for (int h = 1; h < 5; ++h) rsel = (jhalf == h) ? p2[h] : rsel;
    const float kcv = jodd ? rsel.y : rsel.x;

    // --- Phase 6: MBON (dmod precomputed) ---
    mbon_m = 0.5f * mbon_m + 0.5f * dmod * fmaxf(kcv + mb_, 0.f);

    // --- Phase 7: batch-issue mbon broadcasts; decoder rowsums start the cover ---
    float bm[NM];
    #pragma unroll
    for (int m = 0; m < NM; ++m) bm[m] = bcast(base4 + 4 * m, mbon_m);
    const float q0 = rowsum16(mbon_m * dw0) + db0;
    const float q1 = rowsum16(mbon_m * dw1) + db1;

    // --- Phase 7.5: DEFERRED plasticity trace of step t-1 -- 40 pk insts of
    //     independent work covering the mbon-bcast latency.
    //     Bq += kcn_old*sldv - lkc_old*sdvec   (scaled space absorbs the 0.125).
    //     Uses sldv (post-phase-3) and sdvec BEFORE phase 9 overwrites it.
    //     At t=0: ko2=lo2=0 -> adds exact zeros.
    {
      const float ka[4] = { ko2[0].x, ko2[0].y, ko2[1].x, ko2[1].y };
      const float la[4] = { lo2[0].x, lo2[0].y, lo2[1].x, lo2[1].y };
      #pragma unroll
      for (int i = 0; i < 4; ++i) {
        #pragma unroll
        for (int h = 0; h < 5; ++h)
          wct[i][h] = (wct[i][h] + ka[i] * sldv[h]) - la[i] * sdvec[h];
      }
    }

    // --- Phase 8: DAN accumulate (split chain) ---
    float dpA = dp2.x + fmaf(cx, cw, db_);
    float dpB = dp2.y;
    #pragma unroll
    for (int m = 0; m < NM; m += 2) {
      dpA = fmaf(bm[m],     dmw[m],     dpA);
      dpB = fmaf(bm[m + 1], dmw[m + 1], dpB);
    }
    dan_m = 0.5f * dan_m + 0.5f * fmaxf(dpA + dpB, 0.f);

    // --- Phase 9: issue SCALED dan broadcast; consumed at Phase 3 of step t+1 ---
    const float dq = 0.125f * dan_m;
    #pragma unroll
    for (int e = 0; e < 5; ++e) {
      sdvec[e].x = bcast(base4 + 8 * e,     dq);
      sdvec[e].y = bcast(base4 + 8 * e + 4, dq);
    }

    // --- Phase 10: store (independent; adds cover for the dan broadcast) ---
    if (j == 0) {
      float2 st; st.x = q0; st.y = q1;
      *reinterpret_cast<float2*>(out + ((size_t)t * B + b) * 2) = st;
    }
  }
}

extern "C" void kernel_launch(void* const* d_in, const int* in_sizes, int n_in,
                              void* d_out, int out_size, void* d_ws, size_t ws_size,
                              hipStream_t stream) {
  const float* odor   = (const float*)d_in[0];
  const float* ctx    = (const float*)d_in[1];
  const float* pn_w   = (const float*)d_in[2];
  const float* kn_b   = (const float*)d_in[3];
  const float* apl_w  = (const float*)d_in[4];
  const float* apl_b  = (const float*)d_in[5];
  const float* mdw    = (const float*)d_in[6];
  const float* mbon_b = (const float*)d_in[7];
  const float* dmw    = (const float*)d_in[8];
  const float* ddw    = (const float*)d_in[9];
  const float* dcw    = (const float*)d_in[10];
  const float* dan_b  = (const float*)d_in[11];
  const float* decW   = (const float*)d_in[12];
  const float* decb   = (const float*)d_in[13];
  const float* kcw0   = (const float*)d_in[14];
  const float* wact0  = (const float*)d_in[15];
  float* out = (float*)d_out;

  const int B = in_sizes[14] / (KN * NM);   // kc_weight0 is [B,50,10]
  const int T = in_sizes[0] / (B * 3);      // odor is [T,B,3]

  const int batches_per_block = 256 / LPB;  // 16
  dim3 grid((B + batches_per_block - 1) / batches_per_block);
  dim3 block(256);
  hipLaunchKernelGGL(fly_kernel, grid, block, 0, stream,
                     odor, ctx, pn_w, kn_b, apl_w, apl_b,
                     mdw, mbon_b, dmw, ddw, dcw, dan_b,
                     decW, decb, kcw0, wact0, out, B, T);
}